// Round 2
// baseline (250.084 us; speedup 1.0000x reference)
//
#include <hip/hip_runtime.h>
#include <hip/hip_bf16.h>

typedef __bf16 bf16x8 __attribute__((ext_vector_type(8)));
typedef float f32x16 __attribute__((ext_vector_type(16)));

#define NQ     10
#define M_ROWS 16384
#define N_COLS 1024
#define K_DIM  4096

// ---------------------------------------------------------------- helpers
__device__ __forceinline__ void gload_lds16(const __hip_bfloat16* g, __hip_bfloat16* l) {
  __builtin_amdgcn_global_load_lds(
      (const __attribute__((address_space(1))) void*)g,
      (__attribute__((address_space(3))) void*)l,
      16, 0, 0);
}

// ---------------------------------------------------------------- prep (fused)
// blocks [0,4096): W2 fp32->bf16
// blocks [4096,4112): Wq[kcol][0..15] = bf16(W1[kcol][j]) (j<10), 0 pad
// blocks [4112,4176): Qb[row][0..15]  = bf16(q_j(row)) closed-form, 0 pad
__global__ void __launch_bounds__(256) prep(const float* __restrict__ W1,
                                            const float* __restrict__ W2,
                                            const float* __restrict__ x,
                                            const float* __restrict__ qp,
                                            __hip_bfloat16* __restrict__ W2b,
                                            __hip_bfloat16* __restrict__ Wq,
                                            __hip_bfloat16* __restrict__ Qb) {
  const int b = blockIdx.x;
  const int tid = threadIdx.x;
  if (b < 4096) {
    int i = (b * 256 + tid) * 4;
    float4 v = *(const float4*)(W2 + i);
    union { __hip_bfloat16 h[4]; uint2 u; } p;
    p.h[0] = __float2bfloat16(v.x);
    p.h[1] = __float2bfloat16(v.y);
    p.h[2] = __float2bfloat16(v.z);
    p.h[3] = __float2bfloat16(v.w);
    *(uint2*)(W2b + i) = p.u;
  } else if (b < 4112) {
    int kcol = (b - 4096) * 256 + tid;
    union { __hip_bfloat16 h[16]; uint4 u[2]; } p;
#pragma unroll
    for (int j = 0; j < NQ; j++) p.h[j] = __float2bfloat16(W1[kcol * NQ + j]);
#pragma unroll
    for (int j = NQ; j < 16; j++) p.h[j] = __float2bfloat16(0.f);
    *(uint4*)(Wq + kcol * 16) = p.u[0];
    *(uint4*)(Wq + kcol * 16 + 8) = p.u[1];
  } else {
    int row = (b - 4112) * 256 + tid;
    float c[NQ];
#pragma unroll
    for (int j = 0; j < NQ; j++) c[j] = cosf(x[row * NQ + j] + qp[j]);
    float q[NQ];
    float prod19 = 1.f;
#pragma unroll
    for (int j = 1; j < NQ; j++) prod19 *= c[j];
    q[0] = prod19;
    float pref = c[0];
#pragma unroll
    for (int k = 1; k < NQ; k++) { pref *= c[k]; q[k] = pref; }
    union { __hip_bfloat16 h[16]; uint4 u[2]; } p;
#pragma unroll
    for (int j = 0; j < NQ; j++) p.h[j] = __float2bfloat16(q[j]);
#pragma unroll
    for (int j = NQ; j < 16; j++) p.h[j] = __float2bfloat16(0.f);
    *(uint4*)(Qb + row * 16) = p.u[0];
    *(uint4*)(Qb + row * 16 + 8) = p.u[1];
  }
}

// ---------------------------------------------------------------- fused gemm, 8-phase
// C = relu(Q @ W1^T) @ W2^T.  256x256 block tile, 8 waves (2Mx4N, 128x64 each),
// BK=64, double-buffered As/Bs (128 KiB LDS, 1 block/CU, grid 256 = 1/CU).
// Per K-tile: 4 phases, each {ds_read frags | stage issue | (mini h-MFMA) ->
// raw s_barrier -> asm lgkmcnt(0) + sched_barrier -> setprio(1) + 8 MFMA ->
// s_barrier}.  NO memory-clobber fences anywhere in the loop (round-1 lesson:
// they force vmcnt drains and kill the counted-vmcnt pipeline).  One counted
// s_waitcnt vmcnt(2) per tile: outstanding at that point = 4 Bs STAGEs (oldest)
// + 2 Wq prefetch loads (newest); vmcnt(2) drains exactly the STAGEs.
// Cross-wave LDS visibility: each MINI ds_write is drained by its own wave's
// next-phase lgkmcnt(0), >=1 barrier before any other wave reads it.
__global__ void __launch_bounds__(512, 2) gemm_fused(const __hip_bfloat16* __restrict__ Qb,
                                                     const __hip_bfloat16* __restrict__ Wq,
                                                     const __hip_bfloat16* __restrict__ B,
                                                     float* __restrict__ C) {
  __shared__ __align__(16) __hip_bfloat16 As[2][256 * 64];   // 2 x 32 KB
  __shared__ __align__(16) __hip_bfloat16 Bs[2][256 * 64];   // 2 x 32 KB

  const int tid  = threadIdx.x;
  const int wave = tid >> 6;           // 0..7
  const int lane = tid & 63;
  const int l31  = lane & 31;
  const int l5   = lane >> 5;
  const int l7   = l31 & 7;
  const int wm   = (wave >> 2) * 128;  // 2 wave-rows x 128
  const int wn   = (wave & 3) * 64;    // 4 wave-cols x 64

  // XCD decode: each XCD owns one 256-col B panel (2 MB, L2-fit) x 32 row tiles
  const int L    = blockIdx.x;          // 256 blocks
  const int xcd  = L & 7;
  const int idx  = L >> 3;              // 0..31
  const int col0 = (xcd >> 1) * 256;    // 4 col panels, 2 XCDs each
  const int row0 = (((xcd & 1) << 5) + idx) * 256;   // 64 row tiles

  const int ldrow = lane >> 3;                      // staging row 0..7
  const int ldc   = (((lane & 7) ^ ldrow) << 3);    // pre-swizzled global chunk

  // mini-GEMM B-operand frag (loop-invariant): Qb[hrow=row0+wave*32+l31][q=l5*8+j]
  const bf16x8 qb = *(const bf16x8*)(Qb + (row0 + wave * 32 + l31) * 16 + l5 * 8);

  f32x16 acc[4][2];
#pragma unroll
  for (int i = 0; i < 4; i++)
#pragma unroll
    for (int j = 0; j < 2; j++)
#pragma unroll
      for (int r = 0; r < 16; r++) acc[i][j][r] = 0.f;

#define WQF(t, kt) (*(const bf16x8*)(Wq + ((t) * 64 + (kt) * 32 + l31) * 16 + l5 * 8))

  // wave w, instr i stages Bs cols [w*32+i*8, +8) x 64 k (XOR-swizzled via source)
#define STAGE(bw, ts, i)                                                              \
  gload_lds16(B + (col0 + wave * 32 + (i) * 8 + ldrow) * K_DIM + (ts) * 64 + ldc,     \
              &Bs[bw][(wave * 32 + (i) * 8) * 64])

  // mini h-MFMA: D[kcol][hrow]; relu+cvt -> XOR-swizzled As[bw]
#define MINI(bw, wqf, kt) do {                                                        \
    f32x16 d_;                                                                        \
    _Pragma("unroll") for (int r_ = 0; r_ < 16; r_++) d_[r_] = 0.f;                   \
    d_ = __builtin_amdgcn_mfma_f32_32x32x16_bf16((wqf), qb, d_, 0, 0, 0);             \
    const int hb_ = (wave * 32 + l31) * 64;                                           \
    _Pragma("unroll") for (int q_ = 0; q_ < 4; q_++) {                                \
      union { __hip_bfloat16 h[4]; ushort4 u; } p_;                                   \
      _Pragma("unroll") for (int r_ = 0; r_ < 4; r_++)                                \
        p_.h[r_] = __float2bfloat16(fmaxf(d_[4 * q_ + r_], 0.f));                     \
      *(ushort4*)(&As[bw][hb_ + ((((kt) * 4 + q_) ^ l7) << 3) + 4 * l5]) = p_.u;      \
    }                                                                                 \
  } while (0)

#define MFMA_BF16 __builtin_amdgcn_mfma_f32_32x32x16_bf16
#define NOTAIL
#define TAILW asm volatile("s_waitcnt vmcnt(2)" ::)

#define PHASE(br, kki, TAIL) do {                                                     \
    const int ch_ = (((2 * (kki) + l5) ^ l7) << 3);                                   \
    const bf16x8 af0 = *(const bf16x8*)(&As[br][(wm +  0 + l31) * 64 + ch_]);         \
    const bf16x8 af1 = *(const bf16x8*)(&As[br][(wm + 32 + l31) * 64 + ch_]);         \
    const bf16x8 af2 = *(const bf16x8*)(&As[br][(wm + 64 + l31) * 64 + ch_]);         \
    const bf16x8 af3 = *(const bf16x8*)(&As[br][(wm + 96 + l31) * 64 + ch_]);         \
    const bf16x8 bb0 = *(const bf16x8*)(&Bs[br][(wn +  0 + l31) * 64 + ch_]);         \
    const bf16x8 bb1 = *(const bf16x8*)(&Bs[br][(wn + 32 + l31) * 64 + ch_]);         \
    __builtin_amdgcn_s_barrier();                                                     \
    asm volatile("s_waitcnt lgkmcnt(0)" ::);                                          \
    __builtin_amdgcn_sched_barrier(0);                                                \
    __builtin_amdgcn_s_setprio(1);                                                    \
    acc[0][0] = MFMA_BF16(af0, bb0, acc[0][0], 0, 0, 0);                              \
    acc[1][0] = MFMA_BF16(af1, bb0, acc[1][0], 0, 0, 0);                              \
    acc[2][0] = MFMA_BF16(af2, bb0, acc[2][0], 0, 0, 0);                              \
    acc[3][0] = MFMA_BF16(af3, bb0, acc[3][0], 0, 0, 0);                              \
    acc[0][1] = MFMA_BF16(af0, bb1, acc[0][1], 0, 0, 0);                              \
    acc[1][1] = MFMA_BF16(af1, bb1, acc[1][1], 0, 0, 0);                              \
    acc[2][1] = MFMA_BF16(af2, bb1, acc[2][1], 0, 0, 0);                              \
    acc[3][1] = MFMA_BF16(af3, bb1, acc[3][1], 0, 0, 0);                              \
    __builtin_amdgcn_s_setprio(0);                                                    \
    TAIL;                                                                             \
    __builtin_amdgcn_s_barrier();                                                     \
  } while (0)

  // one K-tile: read buf br, build buf bw for tile t+1, prefetch Wq[t+2]
#define TILE(br, bw, wqu0, wqu1, wqp0, wqp1, t) do {                                  \
    STAGE(bw, (t) + 1, 0); STAGE(bw, (t) + 1, 1);                                     \
    MINI(bw, wqu0, 0);                                                                \
    PHASE(br, 0, NOTAIL);                                                             \
    STAGE(bw, (t) + 1, 2); STAGE(bw, (t) + 1, 3);                                     \
    MINI(bw, wqu1, 1);                                                                \
    PHASE(br, 1, NOTAIL);                                                             \
    PHASE(br, 2, NOTAIL);                                                             \
    wqp0 = WQF((t) + 2, 0); wqp1 = WQF((t) + 2, 1);                                   \
    PHASE(br, 3, TAILW);                                                              \
  } while (0)

  // ---------------- prologue: stage tile 0 (B + h), preload Wq tiles 0,1
  STAGE(0, 0, 0); STAGE(0, 0, 1); STAGE(0, 0, 2); STAGE(0, 0, 3);
  bf16x8 wqA0 = WQF(0, 0), wqA1 = WQF(0, 1);
  bf16x8 wqB0 = WQF(1, 0), wqB1 = WQF(1, 1);
  MINI(0, wqA0, 0);
  MINI(0, wqA1, 1);
  __syncthreads();   // full drain once: As[0]/Bs[0] ready

  // ---------------- main loop: 64 K-tiles, unrolled by 2 for static buffers/regs.
  // Tail tiles 62/63 prefetch/compute garbage for nonexistent tiles 64/65 --
  // reads stay inside the workspace (spill into Wq/Qb regions), results unread.
  for (int u = 0; u < 32; u++) {
    TILE(0, 1, wqB0, wqB1, wqA0, wqA1, 2 * u);
    TILE(1, 0, wqA0, wqA1, wqB0, wqB1, 2 * u + 1);
  }

  // ---------------- epilogue: C/D layout col=lane&31, row=(reg&3)+8*(reg>>2)+4*l5
#pragma unroll
  for (int fm = 0; fm < 4; fm++) {
#pragma unroll
    for (int fn = 0; fn < 2; fn++) {
      const int colb = col0 + wn + fn * 32 + l31;
      const int rowb = row0 + wm + fm * 32 + 4 * l5;
#pragma unroll
      for (int reg = 0; reg < 16; reg++) {
        int row = rowb + (reg & 3) + 8 * (reg >> 2);
        C[row * N_COLS + colb] = acc[fm][fn][reg];
      }
    }
  }
}

// ---------------------------------------------------------------- launch
extern "C" void kernel_launch(void* const* d_in, const int* in_sizes, int n_in,
                              void* d_out, int out_size, void* d_ws, size_t ws_size,
                              hipStream_t stream) {
  const float* x  = (const float*)d_in[0];   // 32*512*10
  const float* qp = (const float*)d_in[1];   // 10
  const float* W1 = (const float*)d_in[2];   // 4096*10
  const float* W2 = (const float*)d_in[3];   // 1024*4096
  float* out = (float*)d_out;                // 32*512*1024 fp32

  char* ws = (char*)d_ws;
  __hip_bfloat16* W2b = (__hip_bfloat16*)ws;                 // 8388608 B
  __hip_bfloat16* Wq  = (__hip_bfloat16*)(ws + 8388608);     // 131072 B (4096x16)
  __hip_bfloat16* Qb  = (__hip_bfloat16*)(ws + 8519680);     // 524288 B (16384x16)

  prep<<<4176, 256, 0, stream>>>(W1, W2, x, qp, W2b, Wq, Qb);
  gemm_fused<<<256, 512, 0, stream>>>(Qb, Wq, W2b, out);
}

// Round 3
// 245.519 us; speedup vs baseline: 1.0186x; 1.0186x over previous
//
#include <hip/hip_runtime.h>
#include <hip/hip_bf16.h>

typedef __bf16 bf16x8 __attribute__((ext_vector_type(8)));
typedef float f32x16 __attribute__((ext_vector_type(16)));

#define NQ     10
#define M_ROWS 16384
#define N_COLS 1024
#define K_DIM  4096

// ---------------------------------------------------------------- helpers
__device__ __forceinline__ void gload_lds16(const __hip_bfloat16* g, __hip_bfloat16* l) {
  __builtin_amdgcn_global_load_lds(
      (const __attribute__((address_space(1))) void*)g,
      (__attribute__((address_space(3))) void*)l,
      16, 0, 0);
}

// ---------------------------------------------------------------- prep (fused)
// blocks [0,4096): W2 fp32->bf16
// blocks [4096,4112): Wq[kcol][0..15] = bf16(W1[kcol][j]) (j<10), 0 pad
// blocks [4112,4176): Qb[row][0..15]  = bf16(q_j(row)) closed-form, 0 pad
__global__ void __launch_bounds__(256) prep(const float* __restrict__ W1,
                                            const float* __restrict__ W2,
                                            const float* __restrict__ x,
                                            const float* __restrict__ qp,
                                            __hip_bfloat16* __restrict__ W2b,
                                            __hip_bfloat16* __restrict__ Wq,
                                            __hip_bfloat16* __restrict__ Qb) {
  const int b = blockIdx.x;
  const int tid = threadIdx.x;
  if (b < 4096) {
    int i = (b * 256 + tid) * 4;
    float4 v = *(const float4*)(W2 + i);
    union { __hip_bfloat16 h[4]; uint2 u; } p;
    p.h[0] = __float2bfloat16(v.x);
    p.h[1] = __float2bfloat16(v.y);
    p.h[2] = __float2bfloat16(v.z);
    p.h[3] = __float2bfloat16(v.w);
    *(uint2*)(W2b + i) = p.u;
  } else if (b < 4112) {
    int kcol = (b - 4096) * 256 + tid;
    union { __hip_bfloat16 h[16]; uint4 u[2]; } p;
#pragma unroll
    for (int j = 0; j < NQ; j++) p.h[j] = __float2bfloat16(W1[kcol * NQ + j]);
#pragma unroll
    for (int j = NQ; j < 16; j++) p.h[j] = __float2bfloat16(0.f);
    *(uint4*)(Wq + kcol * 16) = p.u[0];
    *(uint4*)(Wq + kcol * 16 + 8) = p.u[1];
  } else {
    int row = (b - 4112) * 256 + tid;
    float c[NQ];
#pragma unroll
    for (int j = 0; j < NQ; j++) c[j] = cosf(x[row * NQ + j] + qp[j]);
    float q[NQ];
    float prod19 = 1.f;
#pragma unroll
    for (int j = 1; j < NQ; j++) prod19 *= c[j];
    q[0] = prod19;
    float pref = c[0];
#pragma unroll
    for (int k = 1; k < NQ; k++) { pref *= c[k]; q[k] = pref; }
    union { __hip_bfloat16 h[16]; uint4 u[2]; } p;
#pragma unroll
    for (int j = 0; j < NQ; j++) p.h[j] = __float2bfloat16(q[j]);
#pragma unroll
    for (int j = NQ; j < 16; j++) p.h[j] = __float2bfloat16(0.f);
    *(uint4*)(Qb + row * 16) = p.u[0];
    *(uint4*)(Qb + row * 16 + 8) = p.u[1];
  }
}

// ---------------------------------------------------------------- fused gemm
// C = relu(Q @ W1^T) @ W2^T.  256x256 block tile, 8 waves (2Mx4N, 128x64 each),
// BK=64, double-buffered As/Bs (128 KiB LDS, 1 block/CU, grid 256 = 1/CU).
//
// Round-2 restructure: REGISTER-PREFETCHED fragments (X/Y named sets).
// Phase p pre-window issues the 6 ds_read_b128 for phase p+1's fragments, so
// the LDS pipe drains UNDER phase p's MFMA cluster instead of serializing
// with it (round-2 diagnosis: read window 2304 cyc/tile and MFMA window
// 2195 cyc/tile were barrier-disjoint -> 6881 cyc/tile wall).
// Per phase: {MINI/STAGE; 6 ds_reads -> other set} -> s_barrier ->
// lgkmcnt(6) (drains all but the 6 new reads, incl. MINI writes issued
// before them) -> sched_barrier -> setprio(1) + 8 MFMA on current set ->
// s_barrier.  Phase 3 pre-reads NEXT tile's phase-0 frags from the other
// LDS buffer; safe because vmcnt(0) at end of phase 2 drains all STAGEs
// (WQF issued in phase-1 pre-window so this is ~free) and MINI writes were
// lgkm-drained >=2 barriers earlier.
__global__ void __launch_bounds__(512, 2) gemm_fused(const __hip_bfloat16* __restrict__ Qb,
                                                     const __hip_bfloat16* __restrict__ Wq,
                                                     const __hip_bfloat16* __restrict__ B,
                                                     float* __restrict__ C) {
  __shared__ __align__(16) __hip_bfloat16 As[2][256 * 64];   // 2 x 32 KB
  __shared__ __align__(16) __hip_bfloat16 Bs[2][256 * 64];   // 2 x 32 KB

  const int tid  = threadIdx.x;
  const int wave = tid >> 6;           // 0..7
  const int lane = tid & 63;
  const int l31  = lane & 31;
  const int l5   = lane >> 5;
  const int l7   = l31 & 7;
  const int wm   = (wave >> 2) * 128;  // 2 wave-rows x 128
  const int wn   = (wave & 3) * 64;    // 4 wave-cols x 64

  // XCD decode: each XCD owns one 256-col B panel (2 MB, L2-fit) x 32 row tiles
  const int L    = blockIdx.x;          // 256 blocks
  const int xcd  = L & 7;
  const int idx  = L >> 3;              // 0..31
  const int col0 = (xcd >> 1) * 256;    // 4 col panels, 2 XCDs each
  const int row0 = (((xcd & 1) << 5) + idx) * 256;   // 64 row tiles

  const int ldrow = lane >> 3;                      // staging row 0..7
  const int ldc   = (((lane & 7) ^ ldrow) << 3);    // pre-swizzled global chunk

  // mini-GEMM B-operand frag (loop-invariant): Qb[hrow=row0+wave*32+l31][q=l5*8+j]
  const bf16x8 qb = *(const bf16x8*)(Qb + (row0 + wave * 32 + l31) * 16 + l5 * 8);

  f32x16 acc[4][2];
#pragma unroll
  for (int i = 0; i < 4; i++)
#pragma unroll
    for (int j = 0; j < 2; j++)
#pragma unroll
      for (int r = 0; r < 16; r++) acc[i][j][r] = 0.f;

  // double-buffered fragment register sets (named scalars, rule #20)
  bf16x8 Xa0, Xa1, Xa2, Xa3, Xb0, Xb1;
  bf16x8 Ya0, Ya1, Ya2, Ya3, Yb0, Yb1;

#define WQF(t, kt) (*(const bf16x8*)(Wq + ((t) * 64 + (kt) * 32 + l31) * 16 + l5 * 8))

  // wave w, instr i stages Bs cols [w*32+i*8, +8) x 64 k (XOR-swizzled via source)
#define STAGE(bw, ts, i)                                                              \
  gload_lds16(B + (col0 + wave * 32 + (i) * 8 + ldrow) * K_DIM + (ts) * 64 + ldc,     \
              &Bs[bw][(wave * 32 + (i) * 8) * 64])

  // mini h-MFMA: D[kcol][hrow]; relu+cvt -> XOR-swizzled As[bw]
#define MINI(bw, wqf, kt) do {                                                        \
    f32x16 d_;                                                                        \
    _Pragma("unroll") for (int r_ = 0; r_ < 16; r_++) d_[r_] = 0.f;                   \
    d_ = __builtin_amdgcn_mfma_f32_32x32x16_bf16((wqf), qb, d_, 0, 0, 0);             \
    const int hb_ = (wave * 32 + l31) * 64;                                           \
    _Pragma("unroll") for (int q_ = 0; q_ < 4; q_++) {                                \
      union { __hip_bfloat16 h[4]; ushort4 u; } p_;                                   \
      _Pragma("unroll") for (int r_ = 0; r_ < 4; r_++)                                \
        p_.h[r_] = __float2bfloat16(fmaxf(d_[4 * q_ + r_], 0.f));                     \
      *(ushort4*)(&As[bw][hb_ + ((((kt) * 4 + q_) ^ l7) << 3) + 4 * l5]) = p_.u;      \
    }                                                                                 \
  } while (0)

  // load fragment set SET from buffer buf, k-slice kki (6 x ds_read_b128)
#define LOADF(SET, buf, kki) do {                                                     \
    const int ch_ = (((2 * (kki) + l5) ^ l7) << 3);                                   \
    SET##a0 = *(const bf16x8*)(&As[buf][(wm +  0 + l31) * 64 + ch_]);                 \
    SET##a1 = *(const bf16x8*)(&As[buf][(wm + 32 + l31) * 64 + ch_]);                 \
    SET##a2 = *(const bf16x8*)(&As[buf][(wm + 64 + l31) * 64 + ch_]);                 \
    SET##a3 = *(const bf16x8*)(&As[buf][(wm + 96 + l31) * 64 + ch_]);                 \
    SET##b0 = *(const bf16x8*)(&Bs[buf][(wn +  0 + l31) * 64 + ch_]);                 \
    SET##b1 = *(const bf16x8*)(&Bs[buf][(wn + 32 + l31) * 64 + ch_]);                 \
  } while (0)

#define MFMA_BF16 __builtin_amdgcn_mfma_f32_32x32x16_bf16
#define NOTAIL
#define TAILW asm volatile("s_waitcnt vmcnt(0)" ::)

  // barrier -> counted lgkm wait -> pinned MFMA cluster on SET -> barrier
#define PHASE_CORE(SET, TAIL) do {                                                    \
    __builtin_amdgcn_s_barrier();                                                     \
    asm volatile("s_waitcnt lgkmcnt(6)" ::);                                          \
    __builtin_amdgcn_sched_barrier(0);                                                \
    __builtin_amdgcn_s_setprio(1);                                                    \
    acc[0][0] = MFMA_BF16(SET##a0, SET##b0, acc[0][0], 0, 0, 0);                      \
    acc[1][0] = MFMA_BF16(SET##a1, SET##b0, acc[1][0], 0, 0, 0);                      \
    acc[2][0] = MFMA_BF16(SET##a2, SET##b0, acc[2][0], 0, 0, 0);                      \
    acc[3][0] = MFMA_BF16(SET##a3, SET##b0, acc[3][0], 0, 0, 0);                      \
    acc[0][1] = MFMA_BF16(SET##a0, SET##b1, acc[0][1], 0, 0, 0);                      \
    acc[1][1] = MFMA_BF16(SET##a1, SET##b1, acc[1][1], 0, 0, 0);                      \
    acc[2][1] = MFMA_BF16(SET##a2, SET##b1, acc[2][1], 0, 0, 0);                      \
    acc[3][1] = MFMA_BF16(SET##a3, SET##b1, acc[3][1], 0, 0, 0);                      \
    __builtin_amdgcn_s_setprio(0);                                                    \
    TAIL;                                                                             \
    __builtin_amdgcn_s_barrier();                                                     \
  } while (0)

  // one K-tile: consume buf br, build buf bw for tile t+1, prefetch Wq[t+2].
  // X holds kki 0,2 frags; Y holds kki 1,3 (and next tile's kki 0 goes to X).
#define TILE(br, bw, wqu0, wqu1, wqp0, wqp1, t) do {                                  \
    MINI(bw, wqu0, 0);                                                                \
    STAGE(bw, (t) + 1, 0); STAGE(bw, (t) + 1, 1);                                     \
    LOADF(Y, br, 1);                                                                  \
    PHASE_CORE(X, NOTAIL);                                                            \
    MINI(bw, wqu1, 1);                                                                \
    wqp0 = WQF((t) + 2, 0); wqp1 = WQF((t) + 2, 1);                                   \
    STAGE(bw, (t) + 1, 2); STAGE(bw, (t) + 1, 3);                                     \
    LOADF(X, br, 2);                                                                  \
    PHASE_CORE(Y, NOTAIL);                                                            \
    LOADF(Y, br, 3);                                                                  \
    PHASE_CORE(X, TAILW);                                                             \
    LOADF(X, bw, 0);                                                                  \
    PHASE_CORE(Y, NOTAIL);                                                            \
  } while (0)

  // ---------------- prologue: stage tile 0 (B + h), preload Wq tiles 0,1
  STAGE(0, 0, 0); STAGE(0, 0, 1); STAGE(0, 0, 2); STAGE(0, 0, 3);
  bf16x8 wqA0 = WQF(0, 0), wqA1 = WQF(0, 1);
  bf16x8 wqB0 = WQF(1, 0), wqB1 = WQF(1, 1);
  MINI(0, wqA0, 0);
  MINI(0, wqA1, 1);
  __syncthreads();   // full drain once: As[0]/Bs[0] ready
  LOADF(X, 0, 0);    // tile 0 phase 0 fragments

  // ---------------- main loop: 64 K-tiles, unrolled by 2 for static buffers/regs.
  // Tail tiles 62/63 prefetch/compute garbage for nonexistent tiles 64/65 --
  // reads stay inside the workspace (spill into Wq/Qb regions), results unread.
  for (int u = 0; u < 32; u++) {
    TILE(0, 1, wqB0, wqB1, wqA0, wqA1, 2 * u);
    TILE(1, 0, wqA0, wqA1, wqB0, wqB1, 2 * u + 1);
  }

  // ---------------- epilogue: C/D layout col=lane&31, row=(reg&3)+8*(reg>>2)+4*l5
#pragma unroll
  for (int fm = 0; fm < 4; fm++) {
#pragma unroll
    for (int fn = 0; fn < 2; fn++) {
      const int colb = col0 + wn + fn * 32 + l31;
      const int rowb = row0 + wm + fm * 32 + 4 * l5;
#pragma unroll
      for (int reg = 0; reg < 16; reg++) {
        int row = rowb + (reg & 3) + 8 * (reg >> 2);
        C[row * N_COLS + colb] = acc[fm][fn][reg];
      }
    }
  }
}

// ---------------------------------------------------------------- launch
extern "C" void kernel_launch(void* const* d_in, const int* in_sizes, int n_in,
                              void* d_out, int out_size, void* d_ws, size_t ws_size,
                              hipStream_t stream) {
  const float* x  = (const float*)d_in[0];   // 32*512*10
  const float* qp = (const float*)d_in[1];   // 10
  const float* W1 = (const float*)d_in[2];   // 4096*10
  const float* W2 = (const float*)d_in[3];   // 1024*4096
  float* out = (float*)d_out;                // 32*512*1024 fp32

  char* ws = (char*)d_ws;
  __hip_bfloat16* W2b = (__hip_bfloat16*)ws;                 // 8388608 B
  __hip_bfloat16* Wq  = (__hip_bfloat16*)(ws + 8388608);     // 131072 B (4096x16)
  __hip_bfloat16* Qb  = (__hip_bfloat16*)(ws + 8519680);     // 524288 B (16384x16)

  prep<<<4176, 256, 0, stream>>>(W1, W2, x, qp, W2b, Wq, Qb);
  gemm_fused<<<256, 512, 0, stream>>>(Qb, Wq, W2b, out);
}